// Round 1
// baseline (113.605 us; speedup 1.0000x reference)
//
#include <hip/hip_runtime.h>

// out = 2 * sum((img1-img2)^2) / N,  N = B*C*H*W  (H==W collapses the
// row-mean + col-mean structure to a single full-tensor mean).

#define BLOCK 256
#define GRID  1024   // 4 blocks/CU on 256 CUs; each thread does ~12 float4 pairs

__global__ __launch_bounds__(BLOCK) void partial_sq_sum(
    const float4* __restrict__ a4, const float4* __restrict__ b4,
    long n4, float* __restrict__ partials)
{
    long tid    = (long)blockIdx.x * BLOCK + threadIdx.x;
    long stride = (long)gridDim.x * BLOCK;

    float acc = 0.f;
    for (long i = tid; i < n4; i += stride) {
        float4 a = a4[i];
        float4 b = b4[i];
        float d0 = a.x - b.x;
        float d1 = a.y - b.y;
        float d2 = a.z - b.z;
        float d3 = a.w - b.w;
        acc += d0 * d0 + d1 * d1 + d2 * d2 + d3 * d3;
    }

    // wave64 reduction
    #pragma unroll
    for (int off = 32; off > 0; off >>= 1)
        acc += __shfl_down(acc, off, 64);

    __shared__ float wsum[BLOCK / 64];
    int lane = threadIdx.x & 63;
    int wave = threadIdx.x >> 6;
    if (lane == 0) wsum[wave] = acc;
    __syncthreads();

    if (threadIdx.x == 0) {
        float s = 0.f;
        #pragma unroll
        for (int i = 0; i < BLOCK / 64; ++i) s += wsum[i];
        partials[blockIdx.x] = s;
    }
}

__global__ __launch_bounds__(BLOCK) void final_reduce(
    const float* __restrict__ partials, int nparts,
    const float* __restrict__ a, const float* __restrict__ b,
    long tail_start, long n, float* __restrict__ out, float scale)
{
    float acc = 0.f;
    for (int i = threadIdx.x; i < nparts; i += BLOCK)
        acc += partials[i];

    // scalar tail if n % 4 != 0 (not hit for 16*3*512*512, but safe)
    for (long i = tail_start + threadIdx.x; i < n; i += BLOCK) {
        float d = a[i] - b[i];
        acc += d * d;
    }

    #pragma unroll
    for (int off = 32; off > 0; off >>= 1)
        acc += __shfl_down(acc, off, 64);

    __shared__ float wsum[BLOCK / 64];
    int lane = threadIdx.x & 63;
    int wave = threadIdx.x >> 6;
    if (lane == 0) wsum[wave] = acc;
    __syncthreads();

    if (threadIdx.x == 0) {
        float s = 0.f;
        #pragma unroll
        for (int i = 0; i < BLOCK / 64; ++i) s += wsum[i];
        out[0] = s * scale;
    }
}

extern "C" void kernel_launch(void* const* d_in, const int* in_sizes, int n_in,
                              void* d_out, int out_size, void* d_ws, size_t ws_size,
                              hipStream_t stream) {
    const float* a = (const float*)d_in[0];
    const float* b = (const float*)d_in[1];
    float* out = (float*)d_out;
    long n  = (long)in_sizes[0];
    long n4 = n / 4;

    float* partials = (float*)d_ws;  // GRID floats = 4 KB, deterministic writes (no memset needed)

    partial_sq_sum<<<GRID, BLOCK, 0, stream>>>(
        (const float4*)a, (const float4*)b, n4, partials);

    final_reduce<<<1, BLOCK, 0, stream>>>(
        partials, GRID, a, b, n4 * 4, n, out, 2.0f / (float)n);
}